// Round 7
// baseline (910.596 us; speedup 1.0000x reference)
//
#include <hip/hip_runtime.h>

#define N_NODES 50000
#define N_EDGES 800000
#define D 64
#define NBUCKETS 196                 // ceil(50000/256); dst>>8 in 0..195
#define CBLOCKS 256
#define CHUNK (N_EDGES / CBLOCKS)    // 3125

// ---------- Pass 1: per-dst-bucket counts via LDS histograms ----------------
__global__ void __launch_bounds__(256) count_kernel(
    const int* __restrict__ dst, int* __restrict__ bucketCnt) {
    __shared__ int hist[256];
    int t = threadIdx.x;
    hist[t] = 0;
    __syncthreads();
    int lo = blockIdx.x * CHUNK, hi = lo + CHUNK;
    for (int i = lo + t; i < hi; i += 256)
        atomicAdd(&hist[dst[i] >> 8], 1);
    __syncthreads();
    if (hist[t] > 0) atomicAdd(&bucketCnt[t], hist[t]);
}

// ---------- Pass 2: scan 256 bucket counts -> base + padded cursors ---------
__global__ void __launch_bounds__(256) scan_kernel(
    const int* __restrict__ bucketCnt, int* __restrict__ bucketBase,
    int* __restrict__ cursorPad) {
    __shared__ int s[256];
    int t = threadIdx.x;
    int v = bucketCnt[t];
    s[t] = v;
    __syncthreads();
#pragma unroll
    for (int d = 1; d < 256; d <<= 1) {
        int u = (t >= d) ? s[t - d] : 0;
        __syncthreads();
        s[t] += u;
        __syncthreads();
    }
    int excl = s[t] - v;
    bucketBase[t] = excl;
    cursorPad[t * 16] = excl;
    if (t == 255) bucketBase[256] = s[255];
}

// ---------- Pass 3: scatter packed (src<<8 | dst&255) into dst-bucket runs --
__global__ void __launch_bounds__(256) scatter_kernel(
    const int* __restrict__ src, const int* __restrict__ dst,
    int* __restrict__ cursorPad, int* __restrict__ staged) {
    __shared__ int hist[256];
    __shared__ int curs[256];
    int t = threadIdx.x;
    hist[t] = 0;
    __syncthreads();
    int lo = blockIdx.x * CHUNK, hi = lo + CHUNK;
    for (int i = lo + t; i < hi; i += 256)
        atomicAdd(&hist[dst[i] >> 8], 1);
    __syncthreads();
    if (hist[t] > 0) curs[t] = atomicAdd(&cursorPad[t * 16], hist[t]);
    __syncthreads();
    for (int i = lo + t; i < hi; i += 256) {
        int d = dst[i];
        int b = d >> 8;
        int pos = atomicAdd(&curs[b], 1);
        staged[pos] = (src[i] << 8) | (d & 255);
    }
}

// ---------- Pass 4: within each dst-bucket, sort edges by src-bucket --------
// Converts the accum kernel's X reads from random to ascending-src streaming.
__global__ void __launch_bounds__(256) sort_kernel(
    const int* __restrict__ bucketBase, const int* __restrict__ staged,
    int* __restrict__ staged2) {
    __shared__ int hist[256];
    __shared__ int sc[256];
    __shared__ int curs[256];
    int k = blockIdx.x;
    int t = threadIdx.x;
    int base = bucketBase[k];
    int cnt  = bucketBase[k + 1] - base;
    hist[t] = 0;
    __syncthreads();
    for (int i = t; i < cnt; i += 256)
        atomicAdd(&hist[staged[base + i] >> 16], 1);   // src>>8 == packed>>16
    __syncthreads();
    int v = hist[t];
    sc[t] = v;
    __syncthreads();
#pragma unroll
    for (int d = 1; d < 256; d <<= 1) {
        int u = (t >= d) ? sc[t - d] : 0;
        __syncthreads();
        sc[t] += u;
        __syncthreads();
    }
    curs[t] = sc[t] - v;   // exclusive start of src-bucket t within this run
    __syncthreads();
    for (int i = t; i < cnt; i += 256) {
        int e = staged[base + i];
        int pos = atomicAdd(&curs[e >> 16], 1);
        staged2[base + pos] = e;
    }
}

// ---------- Accumulate: agg rows for one dst-bucket in 64 KB LDS ------------
// One block per dst-bucket (256 nodes x 64 feat = 64 KB). Edges are sorted by
// src-bucket, so X row loads stream through L1/L2 while all 196 blocks sweep
// concurrently. LDS atomic bank pattern = lane%32 -> 2-way alias (free).
__global__ void __launch_bounds__(1024) accum_kernel(
    const float* __restrict__ X, const int* __restrict__ bucketBase,
    const int* __restrict__ staged2, float* __restrict__ agg) {
    __shared__ float acc[256 * D];   // 64 KB
    int k = blockIdx.x;
    int t = threadIdx.x;
    float4* acc4 = (float4*)acc;
    for (int i = t; i < 4096; i += 1024)
        acc4[i] = make_float4(0.f, 0.f, 0.f, 0.f);
    __syncthreads();

    int base = bucketBase[k];
    int cnt  = bucketBase[k + 1] - base;
    int wave = t >> 6, lane = t & 63;

    for (int jb = wave * 64; jb < cnt; jb += 16 * 64) {
        int m = min(64, cnt - jb);                       // wave-uniform
        int idx = jb + (lane < m ? lane : m - 1);
        int p = staged2[base + idx];                     // coalesced batch
#pragma unroll 4
        for (int b = 0; b < m; ++b) {                    // uniform trip count
            int e = __shfl(p, b, 64);                    // exec-uniform shfl
            float v = X[(e >> 8) * D + lane];            // 256 B/wave, src asc
            atomicAdd(&acc[(e & 255) * D + lane], v);    // ds_add_f32
        }
    }
    __syncthreads();

    float4* agg4 = (float4*)agg;
    for (int i = t; i < 4096; i += 1024) {
        int node = k * 256 + (i >> 4);
        if (node < N_NODES) agg4[node * 16 + (i & 15)] = acc4[i];
    }
}

// ---------- Register-blocked dual GEMM --------------------------------------
template<int RELU>
__global__ void __launch_bounds__(256) dual_gemm(
    const float* __restrict__ X, const float* __restrict__ A,
    const float* __restrict__ Wr, const float* __restrict__ Wn,
    const float* __restrict__ bias, float* __restrict__ out) {
    __shared__ float sXT[D][D];
    __shared__ float sAT[D][D];
    __shared__ float sWr[D][D];
    __shared__ float sWn[D][D];

    int tid = threadIdx.x;
    int node0 = blockIdx.x * 64;

#pragma unroll
    for (int i = 0; i < 4; i++) {
        int idx = tid + 256 * i;
        ((float4*)sWr)[idx] = ((const float4*)Wr)[idx];
        ((float4*)sWn)[idx] = ((const float4*)Wn)[idx];
    }
    const float4* X4 = (const float4*)X;
    const float4* A4 = (const float4*)A;
    int nd = tid & 63;
    int gn = min(node0 + nd, N_NODES - 1);
#pragma unroll
    for (int pass = 0; pass < 4; pass++) {
        int kq = (tid >> 6) + pass * 4;
        float4 v = X4[gn * 16 + kq];
        float4 w = A4[gn * 16 + kq];
        sXT[kq * 4 + 0][nd] = v.x; sXT[kq * 4 + 1][nd] = v.y;
        sXT[kq * 4 + 2][nd] = v.z; sXT[kq * 4 + 3][nd] = v.w;
        sAT[kq * 4 + 0][nd] = w.x; sAT[kq * 4 + 1][nd] = w.y;
        sAT[kq * 4 + 2][nd] = w.z; sAT[kq * 4 + 3][nd] = w.w;
    }
    __syncthreads();

    int nq = tid >> 4;
    int cq = tid & 15;
    float4 b4 = ((const float4*)bias)[cq];
    float acc[4][4];
#pragma unroll
    for (int i = 0; i < 4; i++) {
        acc[i][0] = b4.x; acc[i][1] = b4.y; acc[i][2] = b4.z; acc[i][3] = b4.w;
    }

#pragma unroll 16
    for (int k = 0; k < D; k++) {
        float4 xv = *(const float4*)&sXT[k][nq * 4];
        float4 av = *(const float4*)&sAT[k][nq * 4];
        float4 wr = *(const float4*)&sWr[k][cq * 4];
        float4 wn = *(const float4*)&sWn[k][cq * 4];
        float xs[4] = {xv.x, xv.y, xv.z, xv.w};
        float as[4] = {av.x, av.y, av.z, av.w};
        float rs[4] = {wr.x, wr.y, wr.z, wr.w};
        float ns[4] = {wn.x, wn.y, wn.z, wn.w};
#pragma unroll
        for (int i = 0; i < 4; i++)
#pragma unroll
            for (int jj = 0; jj < 4; jj++) {
                acc[i][jj] = fmaf(xs[i], rs[jj], acc[i][jj]);
                acc[i][jj] = fmaf(as[i], ns[jj], acc[i][jj]);
            }
    }

    float4* out4 = (float4*)out;
#pragma unroll
    for (int i = 0; i < 4; i++) {
        int node = node0 + nq * 4 + i;
        if (node < N_NODES) {
            float4 r;
            r.x = acc[i][0]; r.y = acc[i][1]; r.z = acc[i][2]; r.w = acc[i][3];
            if (RELU) {
                r.x = fmaxf(r.x, 0.f); r.y = fmaxf(r.y, 0.f);
                r.z = fmaxf(r.z, 0.f); r.w = fmaxf(r.w, 0.f);
            }
            out4[node * 16 + cq] = r;
        }
    }
}

// ---------- launch ----------------------------------------------------------
extern "C" void kernel_launch(void* const* d_in, const int* in_sizes, int n_in,
                              void* d_out, int out_size, void* d_ws, size_t ws_size,
                              hipStream_t stream) {
    const float* x   = (const float*)d_in[0];
    const int*   edg = (const int*)d_in[1];
    const float* W1r = (const float*)d_in[2];
    const float* W1n = (const float*)d_in[3];
    const float* b1  = (const float*)d_in[4];
    const float* W2r = (const float*)d_in[5];
    const float* W2n = (const float*)d_in[6];
    const float* b2  = (const float*)d_in[7];
    float* out = (float*)d_out;

    const int* src = edg;
    const int* dst = edg + N_EDGES;

    // ws is 256 MiB (measured via harness poison fill) — generous layout.
    int* W          = (int*)d_ws;
    int* bucketCnt  = W;              // 256
    int* bucketBase = W + 256;        // 257
    int* cursorPad  = W + 1024;       // 4096
    int* staged     = W + 8192;       // E
    int* staged2    = staged + N_EDGES;
    float* agg      = (float*)(staged2 + N_EDGES);
    float* h        = out;            // layer-1 activations staged in d_out

    hipMemsetAsync(bucketCnt, 0, 256 * sizeof(int), stream);
    count_kernel<<<CBLOCKS, 256, 0, stream>>>(dst, bucketCnt);
    scan_kernel<<<1, 256, 0, stream>>>(bucketCnt, bucketBase, cursorPad);
    scatter_kernel<<<CBLOCKS, 256, 0, stream>>>(src, dst, cursorPad, staged);
    sort_kernel<<<NBUCKETS, 256, 0, stream>>>(bucketBase, staged, staged2);

    const int MB = (N_NODES + 63) / 64;  // 782

    accum_kernel<<<NBUCKETS, 1024, 0, stream>>>(x, bucketBase, staged2, agg);
    dual_gemm<1><<<MB, 256, 0, stream>>>(x, agg, W1r, W1n, b1, h);
    accum_kernel<<<NBUCKETS, 1024, 0, stream>>>(h, bucketBase, staged2, agg);
    dual_gemm<0><<<MB, 256, 0, stream>>>(h, agg, W2r, W2n, b2, out);
}

// Round 8
// 218.410 us; speedup vs baseline: 4.1692x; 4.1692x over previous
//
#include <hip/hip_runtime.h>

#define N_NODES 50000
#define N_EDGES 800000
#define D 64
#define NBUCKETS 196          // dst>>8, 0..195
#define CBLOCKS 256
#define CHUNK (N_EDGES / CBLOCKS)   // 3125

// bf16 helpers (RNE), bit-level so we don't depend on header semantics.
__device__ __forceinline__ unsigned short f2bf(float f) {
    unsigned u = __float_as_uint(f);
    return (unsigned short)((u + 0x7fffu + ((u >> 16) & 1u)) >> 16);
}
__device__ __forceinline__ float bflo(unsigned u) {   // low bf16 of a dword
    return __uint_as_float(u << 16);
}
__device__ __forceinline__ float bfhi(unsigned u) {   // high bf16 of a dword
    return __uint_as_float(u & 0xffff0000u);
}

// ---------- CSR build (identical to the R6 passing version) -----------------
__global__ void __launch_bounds__(256) count_kernel(
    const int* __restrict__ dst, int* __restrict__ bucketCnt) {
    __shared__ int hist[256];
    int t = threadIdx.x;
    hist[t] = 0;
    __syncthreads();
    int lo = blockIdx.x * CHUNK, hi = lo + CHUNK;
    for (int i = lo + t; i < hi; i += 256)
        atomicAdd(&hist[dst[i] >> 8], 1);
    __syncthreads();
    if (hist[t] > 0) atomicAdd(&bucketCnt[t], hist[t]);
}

__global__ void __launch_bounds__(256) scan_kernel(
    const int* __restrict__ bucketCnt, int* __restrict__ bucketBase,
    int* __restrict__ cursorPad) {
    __shared__ int s[256];
    int t = threadIdx.x;
    int v = bucketCnt[t];
    s[t] = v;
    __syncthreads();
#pragma unroll
    for (int d = 1; d < 256; d <<= 1) {
        int u = (t >= d) ? s[t - d] : 0;
        __syncthreads();
        s[t] += u;
        __syncthreads();
    }
    int excl = s[t] - v;
    bucketBase[t] = excl;
    cursorPad[t * 16] = excl;
    if (t == 255) bucketBase[256] = s[255];
}

__global__ void __launch_bounds__(256) scatter_kernel(
    const int* __restrict__ src, const int* __restrict__ dst,
    int* __restrict__ cursorPad, int* __restrict__ staged) {
    __shared__ int hist[256];
    __shared__ int curs[256];
    int t = threadIdx.x;
    hist[t] = 0;
    __syncthreads();
    int lo = blockIdx.x * CHUNK, hi = lo + CHUNK;
    for (int i = lo + t; i < hi; i += 256)
        atomicAdd(&hist[dst[i] >> 8], 1);
    __syncthreads();
    if (hist[t] > 0) curs[t] = atomicAdd(&cursorPad[t * 16], hist[t]);
    __syncthreads();
    for (int i = lo + t; i < hi; i += 256) {
        int d = dst[i];
        int b = d >> 8;
        int pos = atomicAdd(&curs[b], 1);
        staged[pos] = (src[i] << 8) | (d & 255);
    }
}

__global__ void __launch_bounds__(256) csr_build_kernel(
    const int* __restrict__ bucketBase, const int* __restrict__ staged,
    int* __restrict__ csr, int* __restrict__ startA, int* __restrict__ endA) {
    __shared__ int deg[256];
    __shared__ int sc[256];
    __shared__ int curs[256];
    int k = blockIdx.x;
    int t = threadIdx.x;
    int base = bucketBase[k];
    int cnt  = bucketBase[k + 1] - base;
    deg[t] = 0;
    __syncthreads();
    for (int i = t; i < cnt; i += 256)
        atomicAdd(&deg[staged[base + i] & 255], 1);
    __syncthreads();
    int v = deg[t];
    sc[t] = v;
    __syncthreads();
#pragma unroll
    for (int d = 1; d < 256; d <<= 1) {
        int u = (t >= d) ? sc[t - d] : 0;
        __syncthreads();
        sc[t] += u;
        __syncthreads();
    }
    int start = sc[t] - v;
    int node = k * 256 + t;
    if (node < N_NODES) {
        startA[node] = base + start;
        endA[node]   = base + start + v;
    }
    curs[t] = start;
    __syncthreads();
    for (int i = t; i < cnt; i += 256) {
        int e = staged[base + i];
        int pos = atomicAdd(&curs[e & 255], 1);
        csr[base + pos] = e >> 8;
    }
}

// ---------- Cast x -> bf16 copy ---------------------------------------------
__global__ void __launch_bounds__(256) cast_kernel(
    const float* __restrict__ X, unsigned short* __restrict__ Xbf) {
    int i = blockIdx.x * blockDim.x + threadIdx.x;   // over N*D/4
    const float4* X4 = (const float4*)X;
    float4 v = X4[i];
    ushort4 r;
    r.x = f2bf(v.x); r.y = f2bf(v.y); r.z = f2bf(v.z); r.w = f2bf(v.w);
    ((ushort4*)Xbf)[i] = r;
}

// ---------- Gather (bf16 rows): agg[n] = sum_{j in in(n)} X[j] --------------
// One wave per node; 16 edges / 4 independent 8B loads in flight.
// All __shfl exec-uniform (clamped source in the tail) -- the R5 lesson.
__global__ void __launch_bounds__(256) gather_bf16(
    const unsigned short* __restrict__ Xbf, const int* __restrict__ startA,
    const int* __restrict__ endA, const int* __restrict__ csr,
    float* __restrict__ agg) {
    int tid = threadIdx.x;
    int wave = tid >> 6, lane = tid & 63;
    int node = blockIdx.x * 4 + wave;
    int sub = lane >> 4, fq = lane & 15;
    int j0 = startA[node], je = endA[node];
    float a0 = 0.f, a1 = 0.f, a2 = 0.f, a3 = 0.f;
    for (int jb = j0; jb < je; jb += 64) {          // je wave-uniform
        int idx = jb + lane;
        int p = csr[idx < je ? idx : (je - 1)];     // coalesced index batch
        int m = min(64, je - jb);                   // wave-uniform
        int b = 0;
        for (; b + 16 <= m; b += 16) {
            int i0 = __shfl(p, b + sub, 64);
            int i1 = __shfl(p, b + 4 + sub, 64);
            int i2 = __shfl(p, b + 8 + sub, 64);
            int i3 = __shfl(p, b + 12 + sub, 64);
            uint2 u0 = *(const uint2*)(Xbf + i0 * D + fq * 4);
            uint2 u1 = *(const uint2*)(Xbf + i1 * D + fq * 4);
            uint2 u2 = *(const uint2*)(Xbf + i2 * D + fq * 4);
            uint2 u3 = *(const uint2*)(Xbf + i3 * D + fq * 4);
            a0 += bflo(u0.x) + bflo(u1.x) + bflo(u2.x) + bflo(u3.x);
            a1 += bfhi(u0.x) + bfhi(u1.x) + bfhi(u2.x) + bfhi(u3.x);
            a2 += bflo(u0.y) + bflo(u1.y) + bflo(u2.y) + bflo(u3.y);
            a3 += bfhi(u0.y) + bfhi(u1.y) + bfhi(u2.y) + bfhi(u3.y);
        }
        for (; b < m; b += 4) {                     // uniform condition
            int sidx = b + sub;
            int scl = sidx < m ? sidx : (m - 1);    // active source lane
            int i0 = __shfl(p, scl, 64);            // executed by ALL lanes
            if (sidx < m) {                         // divergence only here
                uint2 u = *(const uint2*)(Xbf + i0 * D + fq * 4);
                a0 += bflo(u.x); a1 += bfhi(u.x);
                a2 += bflo(u.y); a3 += bfhi(u.y);
            }
        }
    }
#pragma unroll
    for (int mk = 16; mk <= 32; mk <<= 1) {
        a0 += __shfl_xor(a0, mk, 64);
        a1 += __shfl_xor(a1, mk, 64);
        a2 += __shfl_xor(a2, mk, 64);
        a3 += __shfl_xor(a3, mk, 64);
    }
    if (sub == 0) ((float4*)agg)[node * 16 + fq] = make_float4(a0, a1, a2, a3);
}

// ---------- Register-blocked dual GEMM (+ optional bf16 side-write) ---------
template<int RELU, int WBF>
__global__ void __launch_bounds__(256) dual_gemm(
    const float* __restrict__ X, const float* __restrict__ A,
    const float* __restrict__ Wr, const float* __restrict__ Wn,
    const float* __restrict__ bias, float* __restrict__ out,
    unsigned short* __restrict__ outBf) {
    __shared__ float sXT[D][D];
    __shared__ float sAT[D][D];
    __shared__ float sWr[D][D];
    __shared__ float sWn[D][D];

    int tid = threadIdx.x;
    int node0 = blockIdx.x * 64;

#pragma unroll
    for (int i = 0; i < 4; i++) {
        int idx = tid + 256 * i;
        ((float4*)sWr)[idx] = ((const float4*)Wr)[idx];
        ((float4*)sWn)[idx] = ((const float4*)Wn)[idx];
    }
    const float4* X4 = (const float4*)X;
    const float4* A4 = (const float4*)A;
    int nd = tid & 63;
    int gn = min(node0 + nd, N_NODES - 1);
#pragma unroll
    for (int pass = 0; pass < 4; pass++) {
        int kq = (tid >> 6) + pass * 4;
        float4 v = X4[gn * 16 + kq];
        float4 w = A4[gn * 16 + kq];
        sXT[kq * 4 + 0][nd] = v.x; sXT[kq * 4 + 1][nd] = v.y;
        sXT[kq * 4 + 2][nd] = v.z; sXT[kq * 4 + 3][nd] = v.w;
        sAT[kq * 4 + 0][nd] = w.x; sAT[kq * 4 + 1][nd] = w.y;
        sAT[kq * 4 + 2][nd] = w.z; sAT[kq * 4 + 3][nd] = w.w;
    }
    __syncthreads();

    int nq = tid >> 4;
    int cq = tid & 15;
    float4 b4 = ((const float4*)bias)[cq];
    float acc[4][4];
#pragma unroll
    for (int i = 0; i < 4; i++) {
        acc[i][0] = b4.x; acc[i][1] = b4.y; acc[i][2] = b4.z; acc[i][3] = b4.w;
    }

#pragma unroll 16
    for (int k = 0; k < D; k++) {
        float4 xv = *(const float4*)&sXT[k][nq * 4];
        float4 av = *(const float4*)&sAT[k][nq * 4];
        float4 wr = *(const float4*)&sWr[k][cq * 4];
        float4 wn = *(const float4*)&sWn[k][cq * 4];
        float xs[4] = {xv.x, xv.y, xv.z, xv.w};
        float as[4] = {av.x, av.y, av.z, av.w};
        float rs[4] = {wr.x, wr.y, wr.z, wr.w};
        float ns[4] = {wn.x, wn.y, wn.z, wn.w};
#pragma unroll
        for (int i = 0; i < 4; i++)
#pragma unroll
            for (int jj = 0; jj < 4; jj++) {
                acc[i][jj] = fmaf(xs[i], rs[jj], acc[i][jj]);
                acc[i][jj] = fmaf(as[i], ns[jj], acc[i][jj]);
            }
    }

    float4* out4 = (float4*)out;
#pragma unroll
    for (int i = 0; i < 4; i++) {
        int node = node0 + nq * 4 + i;
        if (node < N_NODES) {
            float4 r;
            r.x = acc[i][0]; r.y = acc[i][1]; r.z = acc[i][2]; r.w = acc[i][3];
            if (RELU) {
                r.x = fmaxf(r.x, 0.f); r.y = fmaxf(r.y, 0.f);
                r.z = fmaxf(r.z, 0.f); r.w = fmaxf(r.w, 0.f);
            }
            out4[node * 16 + cq] = r;
            if (WBF) {
                ushort4 rb;
                rb.x = f2bf(r.x); rb.y = f2bf(r.y);
                rb.z = f2bf(r.z); rb.w = f2bf(r.w);
                *(ushort4*)(outBf + node * D + cq * 4) = rb;
            }
        }
    }
}

// ---------- launch ----------------------------------------------------------
extern "C" void kernel_launch(void* const* d_in, const int* in_sizes, int n_in,
                              void* d_out, int out_size, void* d_ws, size_t ws_size,
                              hipStream_t stream) {
    const float* x   = (const float*)d_in[0];
    const int*   edg = (const int*)d_in[1];
    const float* W1r = (const float*)d_in[2];
    const float* W1n = (const float*)d_in[3];
    const float* b1  = (const float*)d_in[4];
    const float* W2r = (const float*)d_in[5];
    const float* W2n = (const float*)d_in[6];
    const float* b2  = (const float*)d_in[7];
    float* out = (float*)d_out;

    const int* src = edg;
    const int* dst = edg + N_EDGES;

    // ws (256 MiB available) — generous non-overlapping layout.
    int* W            = (int*)d_ws;
    int* bucketCnt    = W;            // 256
    int* bucketBase   = W + 256;      // 257
    int* cursorPad    = W + 1024;     // 4096
    int* staged       = W + 8192;     // E
    int* csr          = staged + N_EDGES;
    int* startA       = csr + N_EDGES;
    int* endA         = startA + N_NODES;
    float* agg        = (float*)(endA + N_NODES);          // N*D f32
    unsigned short* xbf = (unsigned short*)(agg + (size_t)N_NODES * D);
    unsigned short* hbf = xbf + (size_t)N_NODES * D;
    float* h          = out;          // layer-1 fp32 activations in d_out

    hipMemsetAsync(bucketCnt, 0, 256 * sizeof(int), stream);
    count_kernel<<<CBLOCKS, 256, 0, stream>>>(dst, bucketCnt);
    scan_kernel<<<1, 256, 0, stream>>>(bucketCnt, bucketBase, cursorPad);
    scatter_kernel<<<CBLOCKS, 256, 0, stream>>>(src, dst, cursorPad, staged);
    csr_build_kernel<<<NBUCKETS, 256, 0, stream>>>(bucketBase, staged, csr,
                                                   startA, endA);
    cast_kernel<<<(N_NODES * D / 4 + 255) / 256, 256, 0, stream>>>(x, xbf);

    const int GB = N_NODES / 4;          // 12500
    const int MB = (N_NODES + 63) / 64;  // 782

    gather_bf16<<<GB, 256, 0, stream>>>(xbf, startA, endA, csr, agg);
    dual_gemm<1, 1><<<MB, 256, 0, stream>>>(x, agg, W1r, W1n, b1, h, hbf);
    gather_bf16<<<GB, 256, 0, stream>>>(hbf, startA, endA, csr, agg);
    dual_gemm<0, 0><<<MB, 256, 0, stream>>>(h, agg, W2r, W2n, b2, out, hbf);
}